// Round 2
// baseline (14.135 us; speedup 1.0000x reference)
//
#include <hip/hip_runtime.h>

#define FH 128
#define FW 128
#define TW 32            // tile width  (pixels)
#define TH 8             // tile height (pixels)
#define TILES_X (FW / TW)            // 4
#define TILES_Y (FH / TH)            // 16
#define TILES_PER_IMG (TILES_X * TILES_Y)  // 64
#define MAXN 1024
#define MIN_RADIUS 2

__global__ void __launch_bounds__(256)
mask_gather(const float* __restrict__ boxes,
            const float* __restrict__ scores,
            float* __restrict__ out,
            int N) {
    __shared__ int   s_cnt;
    __shared__ int   s_pack[MAXN];    // cx | cy<<8 | radius<<16
    __shared__ float s_score[MAXN];
    __shared__ float s_ninv[MAXN];    // -1 / (2*sigma^2)

    const int blk = blockIdx.x;
    const int b   = blk / TILES_PER_IMG;
    const int t   = blk % TILES_PER_IMG;
    const int x0  = (t % TILES_X) * TW;
    const int y0  = (t / TILES_X) * TH;
    const int tid = threadIdx.x;

    if (tid == 0) s_cnt = 0;
    __syncthreads();

    // ---- Phase 1: compute box params, compact tile-overlapping boxes to LDS
    for (int n = tid; n < N; n += 256) {
        const float* bx = boxes + (size_t)(b * N + n) * 7;
        const float x = bx[0];
        const float y = bx[1];
        const float w = bx[3];
        const float l = bx[4];

        const float scale = 0.8f;            // VOXEL * OUT_FACTOR
        const float w_fm = w / scale;
        const float l_fm = l / scale;

        bool valid = (w_fm > 0.0f) && (l_fm > 0.0f) &&
                     (w_fm <= 1000.0f) && (l_fm <= 1000.0f);

        // gaussian_radius(height=l_fm, width=w_fm, overlap=0.2), f32 math
        const float h  = l_fm;
        const float wd = w_fm;
        const float ov = 0.2f;

        const float b1  = h + wd;
        const float c1  = wd * h * (1.0f - ov) / (1.0f + ov);
        const float r1  = (b1 + sqrtf(fmaxf(b1 * b1 - 4.0f * c1, 0.0f))) * 0.5f;

        const float b2  = 2.0f * (h + wd);
        const float c2  = (1.0f - ov) * wd * h;
        const float r2  = (b2 + sqrtf(fmaxf(b2 * b2 - 16.0f * c2, 0.0f))) * 0.5f;

        const float a3  = 4.0f * ov;
        const float b3  = -2.0f * ov * (h + wd);
        const float c3  = (ov - 1.0f) * wd * h;
        const float r3  = (b3 + sqrtf(fmaxf(b3 * b3 - 4.0f * a3 * c3, 0.0f))) * 0.5f;

        float r = fminf(fminf(r1, r2), r3);
        if (!valid) r = (float)MIN_RADIUS;
        const int radius = max(MIN_RADIUS, (int)floorf(r));

        // truncation toward zero matches astype(int32) for in-bounds range
        const int cx = (int)((x + 51.2f) / scale);
        const int cy = (int)((y + 51.2f) / scale);
        valid = valid && (cx >= 0) && (cx < FW) && (cy >= 0) && (cy < FH);

        const bool overlap = valid &&
            (cx + radius >= x0) && (cx - radius <= x0 + TW - 1) &&
            (cy + radius >= y0) && (cy - radius <= y0 + TH - 1);

        if (overlap) {
            const float sigma = (2.0f * (float)radius + 1.0f) / 6.0f;
            const float denom = 2.0f * sigma * sigma;
            const int slot = atomicAdd(&s_cnt, 1);   // LDS atomic; order
            s_pack[slot]  = cx | (cy << 8) | (radius << 16);  // irrelevant: max
            s_score[slot] = scores[b * N + n];                // is commutative
            s_ninv[slot]  = -1.0f / denom;
        }
    }
    __syncthreads();

    // ---- Phase 2: each thread owns one pixel, gathers max over survivors
    const int px = x0 + (tid & (TW - 1));
    const int py = y0 + (tid / TW);
    const int cnt = s_cnt;
    const float eps = 1.1920928955078125e-07f;   // finfo(f32).eps

    float m = 0.0f;
    for (int i = 0; i < cnt; ++i) {
        const int p  = s_pack[i];                 // LDS broadcast (uniform addr)
        const int cx = p & 0xff;
        const int cy = (p >> 8) & 0xff;
        const int r  = p >> 16;
        const int dx = px - cx;
        const int dy = py - cy;
        if (abs(dx) <= r && abs(dy) <= r) {
            const float d2 = (float)(dx * dx + dy * dy);
            float g = expf(d2 * s_ninv[i]);
            if (g < eps) g = 0.0f;                // dead in-window, kept literal
            m = fmaxf(m, g * s_score[i]);
        }
    }

    // every output pixel written exactly once -> no memset needed
    out[(size_t)b * FH * FW + py * FW + px] = m;
}

extern "C" void kernel_launch(void* const* d_in, const int* in_sizes, int n_in,
                              void* d_out, int out_size, void* d_ws, size_t ws_size,
                              hipStream_t stream) {
    const float* boxes  = (const float*)d_in[0];
    const float* scores = (const float*)d_in[1];
    float* out = (float*)d_out;

    const int B = out_size / (FH * FW);
    const int N = in_sizes[1] / B;

    mask_gather<<<B * TILES_PER_IMG, 256, 0, stream>>>(boxes, scores, out, N);
}

// Round 3
// 13.760 us; speedup vs baseline: 1.0272x; 1.0272x over previous
//
#include <hip/hip_runtime.h>

#define FH 128
#define FW 128
#define TW 32            // tile width  (pixels)
#define TH 8             // tile height (pixels)
#define TILES_X (FW / TW)                  // 4
#define TILES_PER_IMG ((FW / TW) * (FH / TH))  // 64
#define MAXN 1024
#define MIN_RADIUS 2

template <int NITER>   // NITER > 0: compile-time trip count (N == NITER*256)
__global__ void __launch_bounds__(256)
mask_gather(const float* __restrict__ boxes,
            const float* __restrict__ scores,
            float* __restrict__ out,
            int N) {
    __shared__ int   s_cnt;
    __shared__ int   s_pack[MAXN];    // cx | cy<<8 | radius<<16
    __shared__ float s_score[MAXN];
    __shared__ float s_ninv[MAXN];    // -1 / (2*sigma^2)

    const int blk = blockIdx.x;
    const int b   = blk >> 6;                  // / TILES_PER_IMG
    const int t   = blk & (TILES_PER_IMG - 1);
    const int x0  = (t & (TILES_X - 1)) * TW;
    const int y0  = (t >> 2) * TH;             // t / TILES_X
    const int tid = threadIdx.x;

    if (tid == 0) s_cnt = 0;

    // ---- Phase 1a: issue ALL loads up front (independent -> one L2 round-trip)
    float xv[NITER], yv[NITER], wv[NITER], lv[NITER], sv[NITER];
#pragma unroll
    for (int k = 0; k < NITER; ++k) {
        const int n = tid + (k << 8);
        const float* bx = boxes + (size_t)(b * N + n) * 7;
        xv[k] = bx[0];
        yv[k] = bx[1];
        wv[k] = bx[3];
        lv[k] = bx[4];
        sv[k] = scores[b * N + n];
    }
    __syncthreads();   // covers the s_cnt=0 write

    // ---- Phase 1b: params + compact tile-overlapping boxes to LDS
#pragma unroll
    for (int k = 0; k < NITER; ++k) {
        const float scale = 0.8f;            // VOXEL * OUT_FACTOR
        const float w_fm = wv[k] / scale;
        const float l_fm = lv[k] / scale;

        bool valid = (w_fm > 0.0f) && (l_fm > 0.0f) &&
                     (w_fm <= 1000.0f) && (l_fm <= 1000.0f);

        // gaussian_radius(height=l_fm, width=w_fm, overlap=0.2), f32 math
        const float h  = l_fm;
        const float wd = w_fm;
        const float ov = 0.2f;

        const float b1  = h + wd;
        const float c1  = wd * h * (1.0f - ov) / (1.0f + ov);
        const float r1  = (b1 + sqrtf(fmaxf(b1 * b1 - 4.0f * c1, 0.0f))) * 0.5f;

        const float b2  = 2.0f * (h + wd);
        const float c2  = (1.0f - ov) * wd * h;
        const float r2  = (b2 + sqrtf(fmaxf(b2 * b2 - 16.0f * c2, 0.0f))) * 0.5f;

        const float a3  = 4.0f * ov;
        const float b3  = -2.0f * ov * (h + wd);
        const float c3  = (ov - 1.0f) * wd * h;
        const float r3  = (b3 + sqrtf(fmaxf(b3 * b3 - 4.0f * a3 * c3, 0.0f))) * 0.5f;

        float r = fminf(fminf(r1, r2), r3);
        if (!valid) r = (float)MIN_RADIUS;
        const int radius = max(MIN_RADIUS, (int)floorf(r));

        // truncation toward zero matches astype(int32) for in-bounds range
        const int cx = (int)((xv[k] + 51.2f) / scale);
        const int cy = (int)((yv[k] + 51.2f) / scale);
        valid = valid && (cx >= 0) && (cx < FW) && (cy >= 0) && (cy < FH);

        const bool overlap = valid &&
            (cx + radius >= x0) && (cx - radius <= x0 + TW - 1) &&
            (cy + radius >= y0) && (cy - radius <= y0 + TH - 1);

        if (overlap) {
            const float sigma = (2.0f * (float)radius + 1.0f) / 6.0f;
            const int slot = atomicAdd(&s_cnt, 1);   // order irrelevant: max
            s_pack[slot]  = cx | (cy << 8) | (radius << 16);  // is commutative
            s_score[slot] = sv[k];
            s_ninv[slot]  = -1.0f / (2.0f * sigma * sigma);
        }
    }
    __syncthreads();

    // ---- Phase 2: each thread owns one pixel, gathers max over survivors
    const int px = x0 + (tid & (TW - 1));
    const int py = y0 + (tid >> 5);
    const int cnt = s_cnt;
    const float eps = 1.1920928955078125e-07f;   // finfo(f32).eps

    float m = 0.0f;
    for (int i = 0; i < cnt; ++i) {
        const int p  = s_pack[i];                 // LDS broadcast (uniform addr)
        const int cx = p & 0xff;
        const int cy = (p >> 8) & 0xff;
        const int r  = p >> 16;
        const int dx = px - cx;
        const int dy = py - cy;
        if (abs(dx) <= r && abs(dy) <= r) {
            const float d2 = (float)(dx * dx + dy * dy);
            float g = expf(d2 * s_ninv[i]);
            if (g < eps) g = 0.0f;                // dead in-window, kept literal
            m = fmaxf(m, g * s_score[i]);
        }
    }

    // every output pixel written exactly once -> no memset needed
    out[(size_t)b * FH * FW + py * FW + px] = m;
}

// generic fallback (any N), identical math
__global__ void __launch_bounds__(256)
mask_gather_generic(const float* __restrict__ boxes,
                    const float* __restrict__ scores,
                    float* __restrict__ out,
                    int N) {
    __shared__ int   s_cnt;
    __shared__ int   s_pack[MAXN];
    __shared__ float s_score[MAXN];
    __shared__ float s_ninv[MAXN];

    const int blk = blockIdx.x;
    const int b   = blk >> 6;
    const int t   = blk & (TILES_PER_IMG - 1);
    const int x0  = (t & (TILES_X - 1)) * TW;
    const int y0  = (t >> 2) * TH;
    const int tid = threadIdx.x;

    if (tid == 0) s_cnt = 0;
    __syncthreads();

    for (int n = tid; n < N; n += 256) {
        const float* bx = boxes + (size_t)(b * N + n) * 7;
        const float x = bx[0], y = bx[1], w = bx[3], l = bx[4];
        const float scale = 0.8f;
        const float w_fm = w / scale;
        const float l_fm = l / scale;
        bool valid = (w_fm > 0.0f) && (l_fm > 0.0f) &&
                     (w_fm <= 1000.0f) && (l_fm <= 1000.0f);
        const float h = l_fm, wd = w_fm, ov = 0.2f;
        const float b1 = h + wd;
        const float c1 = wd * h * (1.0f - ov) / (1.0f + ov);
        const float r1 = (b1 + sqrtf(fmaxf(b1 * b1 - 4.0f * c1, 0.0f))) * 0.5f;
        const float b2 = 2.0f * (h + wd);
        const float c2 = (1.0f - ov) * wd * h;
        const float r2 = (b2 + sqrtf(fmaxf(b2 * b2 - 16.0f * c2, 0.0f))) * 0.5f;
        const float a3 = 4.0f * ov;
        const float b3 = -2.0f * ov * (h + wd);
        const float c3 = (ov - 1.0f) * wd * h;
        const float r3 = (b3 + sqrtf(fmaxf(b3 * b3 - 4.0f * a3 * c3, 0.0f))) * 0.5f;
        float r = fminf(fminf(r1, r2), r3);
        if (!valid) r = (float)MIN_RADIUS;
        const int radius = max(MIN_RADIUS, (int)floorf(r));
        const int cx = (int)((x + 51.2f) / scale);
        const int cy = (int)((y + 51.2f) / scale);
        valid = valid && (cx >= 0) && (cx < FW) && (cy >= 0) && (cy < FH);
        const bool overlap = valid &&
            (cx + radius >= x0) && (cx - radius <= x0 + TW - 1) &&
            (cy + radius >= y0) && (cy - radius <= y0 + TH - 1);
        if (overlap) {
            const float sigma = (2.0f * (float)radius + 1.0f) / 6.0f;
            const int slot = atomicAdd(&s_cnt, 1);
            s_pack[slot]  = cx | (cy << 8) | (radius << 16);
            s_score[slot] = scores[b * N + n];
            s_ninv[slot]  = -1.0f / (2.0f * sigma * sigma);
        }
    }
    __syncthreads();

    const int px = x0 + (tid & (TW - 1));
    const int py = y0 + (tid >> 5);
    const int cnt = s_cnt;
    const float eps = 1.1920928955078125e-07f;
    float m = 0.0f;
    for (int i = 0; i < cnt; ++i) {
        const int p  = s_pack[i];
        const int cx = p & 0xff;
        const int cy = (p >> 8) & 0xff;
        const int r  = p >> 16;
        const int dx = px - cx;
        const int dy = py - cy;
        if (abs(dx) <= r && abs(dy) <= r) {
            const float d2 = (float)(dx * dx + dy * dy);
            float g = expf(d2 * s_ninv[i]);
            if (g < eps) g = 0.0f;
            m = fmaxf(m, g * s_score[i]);
        }
    }
    out[(size_t)b * FH * FW + py * FW + px] = m;
}

extern "C" void kernel_launch(void* const* d_in, const int* in_sizes, int n_in,
                              void* d_out, int out_size, void* d_ws, size_t ws_size,
                              hipStream_t stream) {
    const float* boxes  = (const float*)d_in[0];
    const float* scores = (const float*)d_in[1];
    float* out = (float*)d_out;

    const int B = out_size / (FH * FW);
    const int N = in_sizes[1] / B;

    if (N == 1024) {
        mask_gather<4><<<B * TILES_PER_IMG, 256, 0, stream>>>(boxes, scores, out, N);
    } else {
        mask_gather_generic<<<B * TILES_PER_IMG, 256, 0, stream>>>(boxes, scores, out, N);
    }
}